// Round 6
// baseline (194.921 us; speedup 1.0000x reference)
//
#include <hip/hip_runtime.h>

#define TT 2048
#define NB 16
#define FD 128
#define ALPHA 0.2f

typedef __attribute__((ext_vector_type(8))) short short8;
typedef __attribute__((ext_vector_type(4))) float f32x4;

static __device__ __forceinline__ unsigned short f2bf(float f) {
    unsigned u = __float_as_uint(f);
    u += 0x7FFF + ((u >> 16) & 1);          // round-to-nearest-even
    return (unsigned short)(u >> 16);
}
static __device__ __forceinline__ float bf2f(unsigned short s) {
    return __uint_as_float(((unsigned)s) << 16);
}

// Kernel P: pack adj (0/1 int32) -> row-major bitmask bm[row*256 + (j>>3)],
// bit (j&7). Perfectly coalesced loads (lane i at base + 16B*i) + ballot
// packing -> pure BW-bound stream.
__global__ __launch_bounds__(256) void k_pack(const int* __restrict__ adj,
                                              unsigned char* __restrict__ bm)
{
    const int tid = threadIdx.x;
    const int w = tid >> 6, l = tid & 63;
    const int row = blockIdx.x * 4 + w;          // 32768 rows
    const int* ap = adj + (size_t)row * TT;
    unsigned char* op = bm + (size_t)row * 256;

    #pragma unroll
    for (int rd = 0; rd < 8; ++rd) {             // 256 j per round
        int4 q = *reinterpret_cast<const int4*>(ap + rd * 256 + l * 4);
        unsigned long long m0 = __ballot(q.x != 0);
        unsigned long long m1 = __ballot(q.y != 0);
        unsigned long long m2 = __ballot(q.z != 0);
        unsigned long long m3 = __ballot(q.w != 0);
        if (l < 32) {
            unsigned b =
                 ((unsigned)(m0 >> (2 * l)) & 1)
              | (((unsigned)(m1 >> (2 * l)) & 1) << 1)
              | (((unsigned)(m2 >> (2 * l)) & 1) << 2)
              | (((unsigned)(m3 >> (2 * l)) & 1) << 3)
              | (((unsigned)(m0 >> (2 * l + 1)) & 1) << 4)
              | (((unsigned)(m1 >> (2 * l + 1)) & 1) << 5)
              | (((unsigned)(m2 >> (2 * l + 1)) & 1) << 6)
              | (((unsigned)(m3 >> (2 * l + 1)) & 1) << 7);
            op[rd * 32 + l] = (unsigned char)b;
        }
    }
}

// Kernel 0: WT[f][k] = bf16(W[k][f])  (128x128, tiny)
__global__ __launch_bounds__(256) void k_wt(const float* __restrict__ W,
                                            unsigned short* __restrict__ WT)
{
    int fid = blockIdx.x * 256 + threadIdx.x;   // 4096 float4s
    int k = fid >> 5;
    int f = (fid & 31) << 2;
    float4 w4 = *reinterpret_cast<const float4*>(W + k * FD + f);
    WT[(f + 0) * FD + k] = f2bf(w4.x);
    WT[(f + 1) * FD + k] = f2bf(w4.y);
    WT[(f + 2) * FD + k] = f2bf(w4.z);
    WT[(f + 3) * FD + k] = f2bf(w4.w);
}

// Kernel 1: h = x@W (bf16 MFMA, WT from L2), write hT[b][f][t] bf16,
//           s1 = h@a1, s2 = h@a2 (fp32)
__global__ __launch_bounds__(256) void k_h(const float* __restrict__ x,
                                           const unsigned short* __restrict__ WT,
                                           const float* __restrict__ a,
                                           unsigned short* __restrict__ hT,
                                           float* __restrict__ s1,
                                           float* __restrict__ s2)
{
    __shared__ unsigned short hs[128][72];   // h-tile transpose staging

    const int tid = threadIdx.x;
    const int b  = blockIdx.x >> 5;
    const int t0 = (blockIdx.x & 31) << 6;
    const int w = tid >> 6, l = tid & 63, g = l >> 4, r15 = l & 15;

    const float* xrow = x + ((size_t)(b * TT + t0 + w * 16 + r15)) * FD;

    f32x4 acc[8] = {};

    #pragma unroll
    for (int m = 0; m < 4; ++m) {
        const int koff = m * 32 + g * 8;
        float4 xa = *reinterpret_cast<const float4*>(xrow + koff);
        float4 xb = *reinterpret_cast<const float4*>(xrow + koff + 4);
        short8 af;
        af[0] = (short)f2bf(xa.x); af[1] = (short)f2bf(xa.y);
        af[2] = (short)f2bf(xa.z); af[3] = (short)f2bf(xa.w);
        af[4] = (short)f2bf(xb.x); af[5] = (short)f2bf(xb.y);
        af[6] = (short)f2bf(xb.z); af[7] = (short)f2bf(xb.w);
        #pragma unroll
        for (int n = 0; n < 8; ++n) {
            short8 bfr = *reinterpret_cast<const short8*>(WT + (n * 16 + r15) * FD + koff);
            acc[n] = __builtin_amdgcn_mfma_f32_16x16x32_bf16(af, bfr, acc[n], 0, 0, 0);
        }
    }

    // s1/s2 from fp32 accumulators: lane holds h[t0+w*16+4g+r][16n+r15]
    float p1[4] = {0.f, 0.f, 0.f, 0.f}, p2[4] = {0.f, 0.f, 0.f, 0.f};
    #pragma unroll
    for (int n = 0; n < 8; ++n) {
        float a1v = a[n * 16 + r15];
        float a2v = a[FD + n * 16 + r15];
        #pragma unroll
        for (int r = 0; r < 4; ++r) {
            p1[r] += acc[n][r] * a1v;
            p2[r] += acc[n][r] * a2v;
        }
    }
    #pragma unroll
    for (int r = 0; r < 4; ++r) {
        #pragma unroll
        for (int off = 8; off >= 1; off >>= 1) {
            p1[r] += __shfl_xor(p1[r], off);
            p2[r] += __shfl_xor(p2[r], off);
        }
    }
    if (r15 == 0) {
        const int trow = t0 + w * 16 + g * 4;
        #pragma unroll
        for (int r = 0; r < 4; ++r) {
            s1[b * TT + trow + r] = p1[r];
            s2[b * TT + trow + r] = p2[r];
        }
    }

    // transpose h tile through LDS, write hT[b][f][t] coalesced
    #pragma unroll
    for (int n = 0; n < 8; ++n)
        #pragma unroll
        for (int r = 0; r < 4; ++r)
            hs[n * 16 + r15][w * 16 + g * 4 + r] = f2bf(acc[n][r]);
    __syncthreads();

    for (int i = tid; i < 1024; i += 256) {
        int f = i >> 3, c = i & 7;
        short8 v = *reinterpret_cast<const short8*>(&hs[f][c * 8]);
        *reinterpret_cast<short8*>(hT + ((size_t)(b * FD + f)) * TT + t0 + c * 8) = v;
    }
}

// Kernel 2: fused mask+softmax+PV, NO barriers in the main loop.
// Block = 16 i-rows, 4 waves each owning a 512-j quarter x full f=128.
// p computed in registers in A-fragment layout (bitmask bits + s2, L1/L2);
// hT B-frags from L2. Partial numerator/denominator are additive (unstable
// softmax) -> one end-of-kernel LDS reduction. Compiler free to pipeline.
__global__ __launch_bounds__(256, 4) void k_att(const unsigned char* __restrict__ bm,
                                                const unsigned short* __restrict__ hT,
                                                const float* __restrict__ s1,
                                                const float* __restrict__ s2,
                                                float* __restrict__ out)
{
    __shared__ __align__(16) float red[2][16][132];
    __shared__ float dsum[4][16];

    const int tid = threadIdx.x;
    // bijective XCD swizzle: 2048 blocks = 8 XCDs x 256 contiguous
    const int wg = (blockIdx.x & 7) * 256 + (blockIdx.x >> 3);
    const int b  = wg >> 7;
    const int i0 = (wg & 127) << 4;
    const int w = tid >> 6, l = tid & 63, g = l >> 4, r15 = l & 15;

    const int jbeg = w * (TT / 4);                       // wave's j-quarter
    const float s1v = s1[b * TT + i0 + r15];
    const float* s2p = s2 + b * TT + jbeg + g * 8;
    const unsigned short* hTb = hT + (size_t)b * FD * TT + (size_t)r15 * TT
                              + jbeg + g * 8;

    // bitmask: row (i0+r15), bytes [jbeg/8, jbeg/8+64). Byte 4t+g covers
    // step t's j = jbeg+32t+g*8..+8. Four uint4 loads cover all 16 steps.
    const unsigned char* bmp = bm + ((size_t)(b * TT + i0 + r15)) * 256 + w * 64;
    uint4 bq0 = *reinterpret_cast<const uint4*>(bmp);
    uint4 bq1 = *reinterpret_cast<const uint4*>(bmp + 16);
    uint4 bq2 = *reinterpret_cast<const uint4*>(bmp + 32);
    uint4 bq3 = *reinterpret_cast<const uint4*>(bmp + 48);
    unsigned wv[16] = {bq0.x, bq0.y, bq0.z, bq0.w,  bq1.x, bq1.y, bq1.z, bq1.w,
                       bq2.x, bq2.y, bq2.z, bq2.w,  bq3.x, bq3.y, bq3.z, bq3.w};

    f32x4 acc[8] = {};
    float rsum = 0.f;

    #pragma unroll
    for (int t = 0; t < 16; ++t) {                       // 32 j per step
        const unsigned bits = (wv[t] >> (g * 8)) & 0xff; // wv[t] static
        float4 sa = *reinterpret_cast<const float4*>(s2p + t * 32);
        float4 sb = *reinterpret_cast<const float4*>(s2p + t * 32 + 4);
        float csf[8] = {sa.x, sa.y, sa.z, sa.w, sb.x, sb.y, sb.z, sb.w};
        short8 af;
        #pragma unroll
        for (int e = 0; e < 8; ++e) {
            float s = s1v + csf[e];
            s = fmaxf(s, ALPHA * s);                     // leaky_relu
            float p = ((bits >> e) & 1) ? __expf(s) : 0.f;
            unsigned short u = f2bf(p);
            rsum += bf2f(u);                             // denom from rounded p
            af[e] = (short)u;
        }
        const unsigned short* hb = hTb + t * 32;
        #pragma unroll
        for (int n = 0; n < 8; ++n) {
            short8 B = *reinterpret_cast<const short8*>(hb + n * 16 * TT);
            acc[n] = __builtin_amdgcn_mfma_f32_16x16x32_bf16(af, B, acc[n], 0, 0, 0);
        }
    }

    // wave-local row sums (reduce over the 4 k-groups)
    rsum += __shfl_xor(rsum, 16);
    rsum += __shfl_xor(rsum, 32);
    if (l < 16) dsum[w][l] = rsum;

    // two-step LDS reduction of the 4 wave-partials
    if (w < 2) {
        #pragma unroll
        for (int n = 0; n < 8; ++n)
            #pragma unroll
            for (int r = 0; r < 4; ++r)
                red[w][g * 4 + r][n * 16 + r15] = acc[n][r];
    }
    __syncthreads();
    if (w >= 2) {
        #pragma unroll
        for (int n = 0; n < 8; ++n)
            #pragma unroll
            for (int r = 0; r < 4; ++r)
                red[w - 2][g * 4 + r][n * 16 + r15] += acc[n][r];
    }
    __syncthreads();

    // epilogue: 16 rows x 128 cols = 512 float4 over 256 threads
    #pragma unroll
    for (int it = 0; it < 2; ++it) {
        int e = it * 256 + tid;
        int row = e >> 5;
        int c4 = (e & 31) << 2;
        float4 v0 = *reinterpret_cast<const float4*>(&red[0][row][c4]);
        float4 v1 = *reinterpret_cast<const float4*>(&red[1][row][c4]);
        float dn = dsum[0][row] + dsum[1][row] + dsum[2][row] + dsum[3][row];
        float ri = 1.0f / dn;
        float4 o;
        o.x = (v0.x + v1.x) * ri;
        o.y = (v0.y + v1.y) * ri;
        o.z = (v0.z + v1.z) * ri;
        o.w = (v0.w + v1.w) * ri;
        *reinterpret_cast<float4*>(out + ((size_t)(b * TT + i0 + row)) * FD + c4) = o;
    }
}

extern "C" void kernel_launch(void* const* d_in, const int* in_sizes, int n_in,
                              void* d_out, int out_size, void* d_ws, size_t ws_size,
                              hipStream_t stream)
{
    const float* x  = (const float*)d_in[0];
    const int* adj  = (const int*)d_in[1];
    const float* W  = (const float*)d_in[2];
    const float* a  = (const float*)d_in[3];
    float* out = (float*)d_out;

    unsigned short* hT = (unsigned short*)d_ws;                       // 8 MB bf16
    float* s1 = (float*)((char*)d_ws + (size_t)NB * FD * TT * 2);
    float* s2 = s1 + NB * TT;
    unsigned short* WT = (unsigned short*)(s2 + NB * TT);             // 32 KB
    unsigned char* bm = (unsigned char*)(WT + FD * FD);               // 8 MB bitmask

    k_pack<<<NB * TT / 4, 256, 0, stream>>>(adj, bm);
    k_wt  <<<16, 256, 0, stream>>>(W, WT);
    k_h   <<<NB * (TT / 64), 256, 0, stream>>>(x, WT, a, hT, s1, s2);
    k_att <<<NB * (TT / 16), 256, 0, stream>>>(bm, hT, s1, s2, out);
}

// Round 7
// 103.689 us; speedup vs baseline: 1.8799x; 1.8799x over previous
//
#include <hip/hip_runtime.h>

#define TT 2048
#define NB 16
#define FD 128
#define ALPHA 0.2f

typedef __attribute__((ext_vector_type(8))) short short8;
typedef __attribute__((ext_vector_type(4))) float f32x4;
typedef __attribute__((ext_vector_type(16))) float f32x16;

static __device__ __forceinline__ unsigned short f2bf(float f) {
    unsigned u = __float_as_uint(f);
    u += 0x7FFF + ((u >> 16) & 1);          // round-to-nearest-even
    return (unsigned short)(u >> 16);
}
static __device__ __forceinline__ float bf2f(unsigned short s) {
    return __uint_as_float(((unsigned)s) << 16);
}

// Kernel P: pack adj (0/1 int32) -> row-major bitmask bm[row*256 + (j>>3)],
// bit (j&7). Coalesced loads + ballot packing -> pure BW-bound stream.
__global__ __launch_bounds__(256) void k_pack(const int* __restrict__ adj,
                                              unsigned char* __restrict__ bm)
{
    const int tid = threadIdx.x;
    const int w = tid >> 6, l = tid & 63;
    const int row = blockIdx.x * 4 + w;          // 32768 rows
    const int* ap = adj + (size_t)row * TT;
    unsigned char* op = bm + (size_t)row * 256;

    #pragma unroll
    for (int rd = 0; rd < 8; ++rd) {             // 256 j per round
        int4 q = *reinterpret_cast<const int4*>(ap + rd * 256 + l * 4);
        unsigned long long m0 = __ballot(q.x != 0);
        unsigned long long m1 = __ballot(q.y != 0);
        unsigned long long m2 = __ballot(q.z != 0);
        unsigned long long m3 = __ballot(q.w != 0);
        if (l < 32) {
            unsigned b =
                 ((unsigned)(m0 >> (2 * l)) & 1)
              | (((unsigned)(m1 >> (2 * l)) & 1) << 1)
              | (((unsigned)(m2 >> (2 * l)) & 1) << 2)
              | (((unsigned)(m3 >> (2 * l)) & 1) << 3)
              | (((unsigned)(m0 >> (2 * l + 1)) & 1) << 4)
              | (((unsigned)(m1 >> (2 * l + 1)) & 1) << 5)
              | (((unsigned)(m2 >> (2 * l + 1)) & 1) << 6)
              | (((unsigned)(m3 >> (2 * l + 1)) & 1) << 7);
            op[rd * 32 + l] = (unsigned char)b;
        }
    }
}

// Kernel 0: WT[f][k] = bf16(W[k][f])  (128x128, tiny)
__global__ __launch_bounds__(256) void k_wt(const float* __restrict__ W,
                                            unsigned short* __restrict__ WT)
{
    int fid = blockIdx.x * 256 + threadIdx.x;   // 4096 float4s
    int k = fid >> 5;
    int f = (fid & 31) << 2;
    float4 w4 = *reinterpret_cast<const float4*>(W + k * FD + f);
    WT[(f + 0) * FD + k] = f2bf(w4.x);
    WT[(f + 1) * FD + k] = f2bf(w4.y);
    WT[(f + 2) * FD + k] = f2bf(w4.z);
    WT[(f + 3) * FD + k] = f2bf(w4.w);
}

// Kernel 1: h = x@W (bf16 MFMA, WT from L2); write hF in B-FRAGMENT order for
// mfma_f32_32x32x16_bf16: hF[b][j16][n32][lane][e] = h[j=j16*16+8*(lane>>5)+e]
// [f=n32*32+(lane&31)]  (so k_att B-loads are 1KB fully-coalesced).
// Also s1 = h@a1, s2 = h@a2 (fp32).
__global__ __launch_bounds__(256) void k_h(const float* __restrict__ x,
                                           const unsigned short* __restrict__ WT,
                                           const float* __restrict__ a,
                                           unsigned short* __restrict__ hF,
                                           float* __restrict__ s1,
                                           float* __restrict__ s2)
{
    __shared__ unsigned short hs[128][72];   // h-tile transpose staging [f][t]

    const int tid = threadIdx.x;
    const int b  = blockIdx.x >> 5;
    const int t0 = (blockIdx.x & 31) << 6;
    const int w = tid >> 6, l = tid & 63, g = l >> 4, r15 = l & 15;

    const float* xrow = x + ((size_t)(b * TT + t0 + w * 16 + r15)) * FD;

    f32x4 acc[8] = {};

    #pragma unroll
    for (int m = 0; m < 4; ++m) {
        const int koff = m * 32 + g * 8;
        float4 xa = *reinterpret_cast<const float4*>(xrow + koff);
        float4 xb = *reinterpret_cast<const float4*>(xrow + koff + 4);
        short8 af;
        af[0] = (short)f2bf(xa.x); af[1] = (short)f2bf(xa.y);
        af[2] = (short)f2bf(xa.z); af[3] = (short)f2bf(xa.w);
        af[4] = (short)f2bf(xb.x); af[5] = (short)f2bf(xb.y);
        af[6] = (short)f2bf(xb.z); af[7] = (short)f2bf(xb.w);
        #pragma unroll
        for (int n = 0; n < 8; ++n) {
            short8 bfr = *reinterpret_cast<const short8*>(WT + (n * 16 + r15) * FD + koff);
            acc[n] = __builtin_amdgcn_mfma_f32_16x16x32_bf16(af, bfr, acc[n], 0, 0, 0);
        }
    }

    // s1/s2 from fp32 accumulators: lane holds h[t0+w*16+4g+r][16n+r15]
    float p1[4] = {0.f, 0.f, 0.f, 0.f}, p2[4] = {0.f, 0.f, 0.f, 0.f};
    #pragma unroll
    for (int n = 0; n < 8; ++n) {
        float a1v = a[n * 16 + r15];
        float a2v = a[FD + n * 16 + r15];
        #pragma unroll
        for (int r = 0; r < 4; ++r) {
            p1[r] += acc[n][r] * a1v;
            p2[r] += acc[n][r] * a2v;
        }
    }
    #pragma unroll
    for (int r = 0; r < 4; ++r) {
        #pragma unroll
        for (int off = 8; off >= 1; off >>= 1) {
            p1[r] += __shfl_xor(p1[r], off);
            p2[r] += __shfl_xor(p2[r], off);
        }
    }
    if (r15 == 0) {
        const int trow = t0 + w * 16 + g * 4;
        #pragma unroll
        for (int r = 0; r < 4; ++r) {
            s1[b * TT + trow + r] = p1[r];
            s2[b * TT + trow + r] = p2[r];
        }
    }

    // stage h tile (bf16) into LDS transposed: hs[f][t_local]
    #pragma unroll
    for (int n = 0; n < 8; ++n)
        #pragma unroll
        for (int r = 0; r < 4; ++r)
            hs[n * 16 + r15][w * 16 + g * 4 + r] = f2bf(acc[n][r]);
    __syncthreads();

    // write fragment-linear hF: 4 j16-tiles x 4 n32 x 64 lanes x 16B = 16KB
    #pragma unroll
    for (int it = 0; it < 4; ++it) {
        int idx = it * 256 + tid;            // 0..1023
        int lp = idx & 63;                   // consumer lane
        int frag = idx >> 6;                 // 0..15
        int n32 = frag & 3, tl = frag >> 2;  // local j16 tile
        int fsrc = n32 * 32 + (lp & 31);
        int tsrc = tl * 16 + (lp >> 5) * 8;
        short8 v = *reinterpret_cast<const short8*>(&hs[fsrc][tsrc]);
        *reinterpret_cast<short8*>(
            hF + (((size_t)(b * 128 + (t0 >> 4) + tl)) * 4 + n32) * 512 + lp * 8) = v;
    }
}

// Kernel 2: fused mask+softmax+PV, barrier-free main loop.
// Block = 32 i-rows, 4 waves each owning a 512-j quarter x full f=128.
// mfma_f32_32x32x16_bf16: A = P[32i x 16j] built in registers from bitmask+s2;
// B = 1KB coalesced fragment loads from hF (L2), depth-1 register dbuf.
// Unstable-softmax partials additive -> one end-of-kernel LDS reduction.
__global__ __launch_bounds__(256, 4) void k_att(const unsigned char* __restrict__ bm,
                                                const unsigned short* __restrict__ hF,
                                                const float* __restrict__ s1,
                                                const float* __restrict__ s2,
                                                float* __restrict__ out)
{
    __shared__ __align__(16) float red[2][32][132];   // 33.8 KB
    __shared__ float dsum[4][32];

    const int tid = threadIdx.x;
    // bijective XCD swizzle: 1024 blocks = 8 XCDs x 128 contiguous
    const int wg = (blockIdx.x & 7) * 128 + (blockIdx.x >> 3);
    const int b  = wg >> 6;
    const int i0 = (wg & 63) << 5;
    const int w = tid >> 6, l = tid & 63;
    const int il = l & 31, h = l >> 5;        // A row, k-half
    const int hsh = h * 8;

    const int jbeg = w * (TT / 4);
    const float s1v = s1[b * TT + i0 + il];
    const float* s2p = s2 + b * TT + jbeg + h * 8;
    const unsigned char* bmrow = bm + ((size_t)(b * TT + i0 + il)) * 256 + w * 64;
    const unsigned short* hfp = hF + ((size_t)(b * 128 + (jbeg >> 4))) * 4 * 512 + l * 8;

    f32x16 acc[4] = {};
    float rsum = 0.f;

    short8 bb[2][4];                          // depth-1 B double-buffer
    #pragma unroll
    for (int n = 0; n < 4; ++n)
        bb[0][n] = *reinterpret_cast<const short8*>(hfp + (size_t)n * 512);

    uint4 bq;

    #pragma unroll
    for (int t = 0; t < 32; ++t) {            // 16 j per step
        const int cur = t & 1;
        if (t < 31) {                         // prefetch next step's B frags
            #pragma unroll
            for (int n = 0; n < 4; ++n)
                bb[cur ^ 1][n] = *reinterpret_cast<const short8*>(
                    hfp + (size_t)((t + 1) * 4 + n) * 512);
        }
        if ((t & 7) == 0)                     // bitmask: 16B covers 8 steps
            bq = *reinterpret_cast<const uint4*>(bmrow + (t >> 3) * 16);
        const int wi = (t & 7) >> 1;          // static word select
        const unsigned wsel = wi == 0 ? bq.x : wi == 1 ? bq.y : wi == 2 ? bq.z : bq.w;
        const unsigned bits = (wsel >> ((t & 1) * 16 + hsh)) & 0xffu;

        float4 sa = *reinterpret_cast<const float4*>(s2p + t * 16);
        float4 sb = *reinterpret_cast<const float4*>(s2p + t * 16 + 4);
        float csf[8] = {sa.x, sa.y, sa.z, sa.w, sb.x, sb.y, sb.z, sb.w};
        short8 af;
        #pragma unroll
        for (int e = 0; e < 8; ++e) {
            float s = s1v + csf[e];
            s = fmaxf(s, ALPHA * s);                     // leaky_relu
            float p = ((bits >> e) & 1) ? __expf(s) : 0.f;
            unsigned short u = f2bf(p);
            rsum += bf2f(u);                             // denom from rounded p
            af[e] = (short)u;
        }
        #pragma unroll
        for (int n = 0; n < 4; ++n)
            acc[n] = __builtin_amdgcn_mfma_f32_32x32x16_bf16(af, bb[cur][n], acc[n], 0, 0, 0);
    }

    // quarter row-sums: combine the two k-halves, store per-wave partials
    rsum += __shfl_xor(rsum, 32);
    if (l < 32) dsum[w][l] = rsum;

    // two-step LDS reduction of the 4 wave-partial accumulators
    if (w < 2) {
        #pragma unroll
        for (int n = 0; n < 4; ++n)
            #pragma unroll
            for (int r = 0; r < 16; ++r) {
                int irow = (r & 3) + 8 * (r >> 2) + 4 * h;
                red[w][irow][n * 32 + il] = acc[n][r];
            }
    }
    __syncthreads();
    if (w >= 2) {
        #pragma unroll
        for (int n = 0; n < 4; ++n)
            #pragma unroll
            for (int r = 0; r < 16; ++r) {
                int irow = (r & 3) + 8 * (r >> 2) + 4 * h;
                red[w - 2][irow][n * 32 + il] += acc[n][r];
            }
    }
    __syncthreads();

    // epilogue: 32 rows x 128 cols = 1024 float4 over 256 threads
    #pragma unroll
    for (int it = 0; it < 4; ++it) {
        int e = it * 256 + tid;
        int row = e >> 5;
        int c4 = (e & 31) << 2;
        float4 v0 = *reinterpret_cast<const float4*>(&red[0][row][c4]);
        float4 v1 = *reinterpret_cast<const float4*>(&red[1][row][c4]);
        float dn = dsum[0][row] + dsum[1][row] + dsum[2][row] + dsum[3][row];
        float ri = 1.0f / dn;
        float4 o;
        o.x = (v0.x + v1.x) * ri;
        o.y = (v0.y + v1.y) * ri;
        o.z = (v0.z + v1.z) * ri;
        o.w = (v0.w + v1.w) * ri;
        *reinterpret_cast<float4*>(out + ((size_t)(b * TT + i0 + row)) * FD + c4) = o;
    }
}

extern "C" void kernel_launch(void* const* d_in, const int* in_sizes, int n_in,
                              void* d_out, int out_size, void* d_ws, size_t ws_size,
                              hipStream_t stream)
{
    const float* x  = (const float*)d_in[0];
    const int* adj  = (const int*)d_in[1];
    const float* W  = (const float*)d_in[2];
    const float* a  = (const float*)d_in[3];
    float* out = (float*)d_out;

    unsigned short* hF = (unsigned short*)d_ws;                       // 8 MB bf16 (fragment-linear)
    float* s1 = (float*)((char*)d_ws + (size_t)NB * FD * TT * 2);
    float* s2 = s1 + NB * TT;
    unsigned short* WT = (unsigned short*)(s2 + NB * TT);             // 32 KB
    unsigned char* bm = (unsigned char*)(WT + FD * FD);               // 8 MB bitmask

    k_pack<<<NB * TT / 4, 256, 0, stream>>>(adj, bm);
    k_wt  <<<16, 256, 0, stream>>>(W, WT);
    k_h   <<<NB * (TT / 64), 256, 0, stream>>>(x, WT, a, hF, s1, s2);
    k_att <<<NB * (TT / 32), 256, 0, stream>>>(bm, hF, s1, s2, out);
}